// Round 11
// baseline (900.334 us; speedup 1.0000x reference)
//
#include <hip/hip_runtime.h>
#include <hip/hip_bf16.h>
#include <hip/hip_cooperative_groups.h>
#include <math.h>

namespace cg = cooperative_groups;

#define DM   1024   // d_model
#define DI   2048   // d_inner
#define DTR  64     // dt_rank
#define DST  16     // d_state
#define NB   2      // batch
#define LL   1024   // seq len
#define MR   (NB*LL)  // 2048 rows
#define XLD  128    // xdb padded leading dim
#define KS   8      // split-K factor for x-proj

typedef __bf16 bf16x8 __attribute__((ext_vector_type(8)));
typedef float  f32x4  __attribute__((ext_vector_type(4)));

__device__ __forceinline__ float siluf(float x) { return x / (1.f + __expf(-x)); }
__device__ __forceinline__ float softplusf(float x) {
    return fmaxf(x, 0.f) + log1pf(__expf(-fabsf(x)));
}
__device__ __forceinline__ unsigned short f2bf(float f) {
    __hip_bfloat16 h = __float2bfloat16(f);
    return *reinterpret_cast<unsigned short*>(&h);
}
__device__ __forceinline__ float bf2f(__hip_bfloat16 h) { return __bfloat162float(h); }
__device__ __forceinline__ float u2f(unsigned short u) {
    return __uint_as_float(((unsigned int)u) << 16);
}

__device__ __forceinline__ void gl2lds16(const __hip_bfloat16* g, __hip_bfloat16* l)
{
    __builtin_amdgcn_global_load_lds(
        (const __attribute__((address_space(1))) unsigned int*)g,
        (__attribute__((address_space(3))) unsigned int*)l, 16, 0, 0);
}

// =================== shared phase bodies ===================

// bf16 MFMA GEMM tile: C[m,n] = sum_k A[m,k]*B[n,k]; 128x128 tile, BK=64,
// 256 thr. XOR-swizzled LDS staging via global_load_lds (zero bank conflicts).
// EPI: 0 = fp32 store (LDS-restaged), 1 = bf16 store, 3 = softplus(+bias) bf16.
template<int EPI>
__device__ __forceinline__ void gemm_tile(
    __hip_bfloat16* smem, int tid,
    const __hip_bfloat16* __restrict__ Az, int lda,
    const __hip_bfloat16* __restrict__ Bz, int ldb,
    void* __restrict__ Cz, int ldc, int K,
    int bm, int bn, const float* __restrict__ bias)
{
    __hip_bfloat16* As = smem;
    __hip_bfloat16* Bs = smem + 128 * 64;
    const int wv   = tid >> 6;
    const int lane = tid & 63;
    const int wr   = (wv >> 1) * 64;
    const int wc   = (wv & 1) * 64;
    const int srow = wv * 32 + (lane >> 3);
    const int cg_  = ((lane & 7) ^ (lane >> 3)) * 8;
    const int fr   = lane & 15;
    const int quad = lane >> 4;
    const int pc0  = (quad ^ (fr & 7)) * 8;
    const int pc1  = ((4 + quad) ^ (fr & 7)) * 8;

    f32x4 acc[4][4] = {};

    for (int k0 = 0; k0 < K; k0 += 64) {
        __syncthreads();
        #pragma unroll
        for (int i = 0; i < 4; ++i) {
            int r = srow + i * 8;
            gl2lds16(Az + (size_t)(bm + r) * lda + k0 + cg_, As + wv * 2048 + i * 512);
            gl2lds16(Bz + (size_t)(bn + r) * ldb + k0 + cg_, Bs + wv * 2048 + i * 512);
        }
        __syncthreads();
        #pragma unroll
        for (int kk = 0; kk < 2; ++kk) {
            const int pc = kk ? pc1 : pc0;
            bf16x8 af[4], bf_[4];
            #pragma unroll
            for (int i = 0; i < 4; ++i) {
                af[i]  = *(const bf16x8*)(As + (wr + i * 16 + fr) * 64 + pc);
                bf_[i] = *(const bf16x8*)(Bs + (wc + i * 16 + fr) * 64 + pc);
            }
            #pragma unroll
            for (int i = 0; i < 4; ++i)
                #pragma unroll
                for (int j = 0; j < 4; ++j)
                    acc[i][j] = __builtin_amdgcn_mfma_f32_16x16x32_bf16(
                        af[i], bf_[j], acc[i][j], 0, 0, 0);
        }
    }

    // epilogue via LDS restage (32 rows x 132 fp32) -> vectorized stores
    float* eps = (float*)smem;
    const int half = wv >> 1;
    const int lrow = tid >> 3;
    const int cseg = (tid & 7) * 16;
    const int gr_  = bm + (lrow >> 4) * 64 + (lrow & 15);
    #pragma unroll
    for (int i = 0; i < 4; ++i) {
        __syncthreads();
        #pragma unroll
        for (int j = 0; j < 4; ++j)
            #pragma unroll
            for (int r = 0; r < 4; ++r)
                eps[(half * 16 + quad * 4 + r) * 132 + wc + j * 16 + fr] = acc[i][j][r];
        __syncthreads();
        float vals[16];
        *(float4*)(vals +  0) = *(const float4*)(eps + lrow * 132 + cseg +  0);
        *(float4*)(vals +  4) = *(const float4*)(eps + lrow * 132 + cseg +  4);
        *(float4*)(vals +  8) = *(const float4*)(eps + lrow * 132 + cseg +  8);
        *(float4*)(vals + 12) = *(const float4*)(eps + lrow * 132 + cseg + 12);
        int gr = gr_ + i * 16;
        int gc = bn + cseg;
        if (EPI == 0) {
            float* dst = (float*)Cz + (size_t)gr * ldc + gc;
            *(float4*)(dst +  0) = *(const float4*)(vals +  0);
            *(float4*)(dst +  4) = *(const float4*)(vals +  4);
            *(float4*)(dst +  8) = *(const float4*)(vals +  8);
            *(float4*)(dst + 12) = *(const float4*)(vals + 12);
        } else {
            unsigned short os[16];
            #pragma unroll
            for (int c = 0; c < 16; ++c) {
                float t = vals[c];
                if (EPI == 3) t = softplusf(t + bias[gc + c]);
                os[c] = f2bf(t);
            }
            unsigned short* dst = (unsigned short*)Cz + (size_t)gr * ldc + gc;
            *(ushort4*)(dst +  0) = *(ushort4*)(os +  0);
            *(ushort4*)(dst +  4) = *(ushort4*)(os +  4);
            *(ushort4*)(dst +  8) = *(ushort4*)(os +  8);
            *(ushort4*)(dst + 12) = *(ushort4*)(os + 12);
        }
    }
}

// depthwise conv(4) + silu; q = flat quad index over [2][MR][DI/4]
__device__ __forceinline__ void conv_body(
    int q, const __hip_bfloat16* __restrict__ xz2,
    const float* __restrict__ fW, const float* __restrict__ fb,
    const float* __restrict__ bW, const float* __restrict__ bb_,
    __hip_bfloat16* __restrict__ xsb2)
{
    const int TQH = MR * DI / 4;
    int dirv = q >= TQH;
    int mq = q - (dirv ? TQH : 0);
    int m = mq >> 9;
    int d = (mq & 511) << 2;
    int t = m & (LL - 1);
    int bb = m >> 10;
    const float* W  = (dirv ? bW : fW) + d * 4;
    const float* Bp = (dirv ? bb_ : fb) + d;
    const __hip_bfloat16* xz = xz2 + (size_t)dirv * MR * 2 * DI;
    float4 bi = *(const float4*)Bp;
    float acc0 = bi.x, acc1 = bi.y, acc2 = bi.z, acc3 = bi.w;
    float w_[16];
    *(float4*)(w_ + 0)  = *(const float4*)(W + 0);
    *(float4*)(w_ + 4)  = *(const float4*)(W + 4);
    *(float4*)(w_ + 8)  = *(const float4*)(W + 8);
    *(float4*)(w_ + 12) = *(const float4*)(W + 12);
    #pragma unroll
    for (int k = 0; k < 4; ++k) {
        int tt = dirv ? (t + 3 - k) : (t - 3 + k);
        bool ok = dirv ? (tt < LL) : (tt >= 0);
        if (ok) {
            ushort4 xv = *(const ushort4*)((const unsigned short*)xz +
                         (size_t)(bb * LL + tt) * 2 * DI + d);
            acc0 = fmaf(w_[0 + k],  u2f(xv.x), acc0);
            acc1 = fmaf(w_[4 + k],  u2f(xv.y), acc1);
            acc2 = fmaf(w_[8 + k],  u2f(xv.z), acc2);
            acc3 = fmaf(w_[12 + k], u2f(xv.w), acc3);
        }
    }
    ushort4 o;
    o.x = f2bf(siluf(acc0)); o.y = f2bf(siluf(acc1));
    o.z = f2bf(siluf(acc2)); o.w = f2bf(siluf(acc3));
    *(ushort4*)((unsigned short*)xsb2 + (size_t)dirv * MR * DI +
                (size_t)m * DI + d) = o;
}

__device__ __forceinline__ void xreduce_body(
    size_t idx, int z, const float* __restrict__ part,
    float* __restrict__ xdb, __hip_bfloat16* __restrict__ xdbt)
{
    const float* p = part + (size_t)z * KS * MR * XLD;
    float4 s = make_float4(0.f, 0.f, 0.f, 0.f);
    #pragma unroll
    for (int ks = 0; ks < KS; ++ks) {
        float4 v = *(const float4*)(p + (size_t)ks * MR * XLD + idx);
        s.x += v.x; s.y += v.y; s.z += v.z; s.w += v.w;
    }
    *(float4*)(xdb + (size_t)z * MR * XLD + idx) = s;
    int c = (int)(idx & (XLD - 1));
    if (c < 64) {
        size_t m = idx >> 7;
        ushort4 o;
        o.x = f2bf(s.x); o.y = f2bf(s.y); o.z = f2bf(s.z); o.w = f2bf(s.w);
        *(ushort4*)((unsigned short*)xdbt + (size_t)z * MR * 64 + m * 64 + c) = o;
    }
}

__device__ __forceinline__ void scan1_body(
    int d, int bb, int dirv, int g, int G, int Cn,
    const __hip_bfloat16* __restrict__ dtf2, const __hip_bfloat16* __restrict__ xsb2,
    const float* __restrict__ xdb2,
    const float* __restrict__ fA, const float* __restrict__ bA,
    float* __restrict__ hend, float* __restrict__ aprod)
{
    const float* A_log = dirv ? bA : fA;
    const __hip_bfloat16* dtf = dtf2 + (size_t)dirv * MR * DI;
    const __hip_bfloat16* xs = xsb2 + (size_t)dirv * MR * DI;
    const float* xdb = xdb2 + (size_t)dirv * MR * XLD;
    size_t hoff = (size_t)dirv * G * (NB * DI * DST);

    float Ad[DST], h[DST], ap[DST];
    bool pw = true;
    #pragma unroll
    for (int s = 0; s < DST; ++s) {
        Ad[s] = -__expf(A_log[d * DST + s]);
        pw = pw && (fabsf(Ad[s] + (float)(s + 1)) < 1e-3f * (s + 1));
        h[s] = 0.f; ap[s] = 1.f;
    }
    int i0 = g * Cn;
    for (int i = 0; i < Cn; ++i) {
        int ii = i0 + i;
        int t = dirv ? (LL - 1 - ii) : ii;
        size_t m = (size_t)bb * LL + t;
        float dtv = bf2f(dtf[m * DI + d]);
        float xv  = bf2f(xs[m * DI + d]);
        const float* bc = xdb + m * XLD;
        float dtx = dtv * xv;
        float dAv[DST];
        if (pw) {
            float r = __expf(-dtv);
            float a = r;
            #pragma unroll
            for (int s = 0; s < DST; ++s) { dAv[s] = a; a *= r; }
        } else {
            #pragma unroll
            for (int s = 0; s < DST; ++s) dAv[s] = __expf(dtv * Ad[s]);
        }
        #pragma unroll
        for (int s = 0; s < DST; ++s) {
            h[s] = fmaf(h[s], dAv[s], dtx * bc[64 + s]);
            ap[s] *= dAv[s];
        }
    }
    size_t base = hoff + ((size_t)(g * NB + bb) * DI + d) * DST;
    #pragma unroll
    for (int s = 0; s < DST; s += 4) {
        *(float4*)(hend  + base + s) = make_float4(h[s], h[s+1], h[s+2], h[s+3]);
        *(float4*)(aprod + base + s) = make_float4(ap[s], ap[s+1], ap[s+2], ap[s+3]);
    }
}

__device__ __forceinline__ void scan2_body(
    int idx, int dirv, float* __restrict__ hend,
    const float* __restrict__ aprod, int G)
{
    const int slab = NB * DI * DST;
    size_t hoff = (size_t)dirv * G * slab;
    float carry = 0.f;
    for (int g = 0; g < G; ++g) {
        size_t off = hoff + (size_t)g * slab + idx;
        float a = aprod[off];
        float e = hend[off];
        hend[off] = carry;
        carry = fmaf(a, carry, e);
    }
}

__device__ __forceinline__ void scan3_body(
    int d, int bb, int dirv, int g, int G, int Cn,
    const __hip_bfloat16* __restrict__ dtf2, const __hip_bfloat16* __restrict__ xsb2,
    const float* __restrict__ xdb2, const __hip_bfloat16* __restrict__ xz2,
    const float* __restrict__ fA, const float* __restrict__ bA,
    const float* __restrict__ fD, const float* __restrict__ bD,
    const float* __restrict__ hin, __hip_bfloat16* __restrict__ ycat)
{
    const float* A_log = dirv ? bA : fA;
    const float* Dskip = dirv ? bD : fD;
    const __hip_bfloat16* dtf = dtf2 + (size_t)dirv * MR * DI;
    const __hip_bfloat16* xs = xsb2 + (size_t)dirv * MR * DI;
    const float* xdb = xdb2 + (size_t)dirv * MR * XLD;
    const __hip_bfloat16* xz = xz2 + (size_t)dirv * MR * 2 * DI;
    size_t hoff = (size_t)dirv * G * (NB * DI * DST);

    float Ad[DST], h[DST];
    bool pw = true;
    size_t base = hoff + ((size_t)(g * NB + bb) * DI + d) * DST;
    #pragma unroll
    for (int s = 0; s < DST; ++s) {
        Ad[s] = -__expf(A_log[d * DST + s]);
        pw = pw && (fabsf(Ad[s] + (float)(s + 1)) < 1e-3f * (s + 1));
        h[s] = hin[base + s];
    }
    float Dsk = Dskip[d];
    int i0 = g * Cn;
    for (int i = 0; i < Cn; ++i) {
        int ii = i0 + i;
        int t = dirv ? (LL - 1 - ii) : ii;
        size_t m = (size_t)bb * LL + t;
        float dtv = bf2f(dtf[m * DI + d]);
        float xv  = bf2f(xs[m * DI + d]);
        const float* bc = xdb + m * XLD;
        float dtx = dtv * xv;
        float dAv[DST];
        if (pw) {
            float r = __expf(-dtv);
            float a = r;
            #pragma unroll
            for (int s = 0; s < DST; ++s) { dAv[s] = a; a *= r; }
        } else {
            #pragma unroll
            for (int s = 0; s < DST; ++s) dAv[s] = __expf(dtv * Ad[s]);
        }
        float yv = 0.f;
        #pragma unroll
        for (int s = 0; s < DST; ++s) {
            h[s] = fmaf(h[s], dAv[s], dtx * bc[64 + s]);
            yv = fmaf(h[s], bc[80 + s], yv);
        }
        float zv = bf2f(xz[m * (2 * DI) + DI + d]);
        ycat[m * (2 * DI) + (size_t)dirv * DI + d] =
            __float2bfloat16((yv + xv * Dsk) * siluf(zv));
    }
}

__device__ __forceinline__ void freduce_body(
    size_t idx, const float* __restrict__ part, const float* __restrict__ x,
    const float* __restrict__ proj_b, float* __restrict__ out)
{
    float4 s = make_float4(0.f, 0.f, 0.f, 0.f);
    #pragma unroll
    for (int z = 0; z < 4; ++z) {
        float4 v = *(const float4*)(part + (size_t)z * MR * DM + idx);
        s.x += v.x; s.y += v.y; s.z += v.z; s.w += v.w;
    }
    float4 xv = *(const float4*)(x + idx);
    float4 pb = *(const float4*)(proj_b + (idx & (DM - 1)));
    float4 o;
    o.x = xv.x + pb.x + s.x;
    o.y = xv.y + pb.y + s.y;
    o.z = xv.z + pb.z + s.z;
    o.w = xv.w + pb.w + s.w;
    *(float4*)(out + idx) = o;
}

// =================== prep kernel (unchanged) ===================
__global__ __launch_bounds__(256) void prep_k(
    const float* __restrict__ s0, const float* __restrict__ s1,
    const float* __restrict__ s2, const float* __restrict__ s3,
    const float* __restrict__ s4, __hip_bfloat16* __restrict__ warena,
    const float* __restrict__ fx, const float* __restrict__ bx,
    __hip_bfloat16* __restrict__ wpb2,
    const float* __restrict__ fo, const float* __restrict__ bo,
    __hip_bfloat16* __restrict__ wot,
    const float* __restrict__ x, const float* __restrict__ lnw,
    const float* __restrict__ lnb, __hip_bfloat16* __restrict__ nb)
{
    __shared__ float pshm[64 * 65];
    const int b = blockIdx.x;
    const int tid = threadIdx.x;

    if (b < 10496) {
        long idx = (long)b * 1024 + tid * 4;
        const float* src; long off;
        if      (idx <  4194304L) { src = s0; off = idx; }
        else if (idx <  8388608L) { src = s1; off = idx -  4194304L; }
        else if (idx < 10485760L) { src = s2; off = idx -  8388608L; }
        else if (idx < 10616832L) { src = s3; off = idx - 10485760L; }
        else                      { src = s4; off = idx - 10616832L; }
        float4 v = *(const float4*)(src + off);
        ushort4 o;
        o.x = f2bf(v.x); o.y = f2bf(v.y); o.z = f2bf(v.z); o.w = f2bf(v.w);
        *(ushort4*)((unsigned short*)warena + idx) = o;
    } else if (b < 10624) {
        int t = b - 10496;
        int z = t >> 6;
        const float* in = z ? bx : fx;
        int idx = ((t & 63) * 256 + tid) * 4;
        int row = idx >> 11;
        ushort4 o = make_ushort4(0, 0, 0, 0);
        if (row < 96) {
            float4 v = *(const float4*)(in + idx);
            o.x = f2bf(v.x); o.y = f2bf(v.y); o.z = f2bf(v.z); o.w = f2bf(v.w);
        }
        *(ushort4*)((unsigned short*)wpb2 + (size_t)z * 128 * DI + idx) = o;
    } else if (b < 11648) {
        int t = b - 10624;
        int z = t >> 9; t &= 511;
        const float* src = z ? bo : fo;
        int c0 = (t & 31) * 64;
        int r0 = (t >> 5) * 64;
        int tc = tid & 63;
        int tr = tid >> 6;
        #pragma unroll
        for (int ii = 0; ii < 16; ++ii) {
            int rl = tr + ii * 4;
            pshm[tc * 65 + rl] = src[(size_t)(r0 + rl) * DI + c0 + tc];
        }
        __syncthreads();
        __hip_bfloat16* dst = wot + (size_t)z * DI * DM;
        #pragma unroll
        for (int ii = 0; ii < 16; ++ii) {
            int cl = tr + ii * 4;
            dst[(size_t)(c0 + cl) * DM + r0 + tc] = __float2bfloat16(pshm[cl * 65 + tc]);
        }
    } else {
        int row = b - 11648;
        const float* xr = x + (size_t)row * DM;
        float4 v = *(const float4*)(xr + tid * 4);
        float s = v.x + v.y + v.z + v.w;
        float q = v.x*v.x + v.y*v.y + v.z*v.z + v.w*v.w;
        #pragma unroll
        for (int off = 32; off > 0; off >>= 1) {
            s += __shfl_xor(s, off, 64);
            q += __shfl_xor(q, off, 64);
        }
        int wv = tid >> 6;
        if ((tid & 63) == 0) { pshm[wv] = s; pshm[8 + wv] = q; }
        __syncthreads();
        s = pshm[0] + pshm[1] + pshm[2] + pshm[3];
        q = pshm[8] + pshm[9] + pshm[10] + pshm[11];
        float mu  = s * (1.f / DM);
        float var = q * (1.f / DM) - mu * mu;
        float rstd = rsqrtf(var + 1e-5f);
        float4 wv4 = *(const float4*)(lnw + tid * 4);
        float4 bv4 = *(const float4*)(lnb + tid * 4);
        ushort4 o;
        o.x = f2bf((v.x - mu) * rstd * wv4.x + bv4.x);
        o.y = f2bf((v.y - mu) * rstd * wv4.y + bv4.y);
        o.z = f2bf((v.z - mu) * rstd * wv4.z + bv4.z);
        o.w = f2bf((v.w - mu) * rstd * wv4.w + bv4.w);
        *(ushort4*)((unsigned short*)nb + (size_t)row * DM + tid * 4) = o;
    }
}

// =================== cooperative mega kernel ===================
struct MegaArgs {
    const __hip_bfloat16 *nb, *wbi, *pwb, *wot, *wpb2, *wdt;
    __hip_bfloat16 *xz2, *wcat, *xsb2, *xdbt, *dtfb, *ycat;
    const float *fW, *fb, *bW, *bb_;
    float *xpart, *xdb2;
    const float *fdtb, *bdtb, *fA, *bA, *fD, *bD;
    float *hend, *aprod;
    const float *x, *proj_b;
    float *fpart, *outp;
    int G, Cn;
};

__global__ __launch_bounds__(256, 2) void mega_k(MegaArgs P)
{
    __shared__ __hip_bfloat16 smem[2 * 128 * 64];
    cg::grid_group grid = cg::this_grid();
    const int tid = threadIdx.x;
    const int bid = blockIdx.x;
    const int gsz = gridDim.x;

    // P0: in-proj (vb<1024) + Wcat (vb in [1024,1280))
    for (int vb = bid; vb < 1280; vb += gsz) {
        const __hip_bfloat16 *Az, *Bz; __hip_bfloat16* Cz; int lda, bm, bn;
        if (vb < 1024) {
            int zz = vb >> 9, rem = vb & 511;
            bm = (rem >> 5) * 128; bn = (rem & 31) * 128;
            Az = P.nb; lda = DM;
            Bz = P.wbi + (size_t)zz * 2 * DI * DM;
            Cz = P.xz2 + (size_t)zz * MR * 2 * DI;
        } else {
            int w = vb - 1024; int zc = w >> 7, rem = w & 127;
            bm = (rem >> 4) * 128; bn = (rem & 15) * 128;
            Az = P.pwb + (size_t)zc * DM; lda = 2 * DM;
            Bz = P.wot + (size_t)zc * DI * DM;
            Cz = P.wcat + (size_t)zc * DI;
        }
        gemm_tile<1>(smem, tid, Az, lda, Bz, DM, Cz, 2 * DI, DM, bm, bn, nullptr);
    }
    grid.sync();

    // P1: conv+silu (8192 vb, 4 channels/thread)
    for (int vb = bid; vb < 8192; vb += gsz)
        conv_body(vb * 256 + tid, P.xz2, P.fW, P.fb, P.bW, P.bb_, P.xsb2);
    grid.sync();

    // P2: x-proj split-K partials (256 vb)
    for (int vb = bid; vb < 256; vb += gsz) {
        int ks = vb & 7, byv = (vb >> 3) & 15, z = vb >> 7;
        int kb = ks * (DI / KS);
        gemm_tile<0>(smem, tid,
            P.xsb2 + (size_t)z * MR * DI + kb, DI,
            P.wpb2 + (size_t)z * 128 * DI + kb, DI,
            P.xpart + ((size_t)z * KS + ks) * MR * XLD, XLD,
            DI / KS, byv * 128, 0, nullptr);
    }
    grid.sync();

    // P3: x-proj reduce (512 vb)
    for (int vb = bid; vb < 512; vb += gsz)
        xreduce_body(((size_t)(vb & 255) * 256 + tid) * 4, vb >> 8,
                     P.xpart, P.xdb2, P.xdbt);
    grid.sync();

    // P4: dt-proj (512 vb)
    for (int vb = bid; vb < 512; vb += gsz) {
        int z = vb >> 8, rem = vb & 255;
        int bm = (rem >> 4) * 128, bn = (rem & 15) * 128;
        gemm_tile<3>(smem, tid,
            P.xdbt + (size_t)z * MR * 64, 64,
            P.wdt + (size_t)z * DI * 64, 64,
            P.dtfb + (size_t)z * MR * DI, DI,
            64, bm, bn, z ? P.bdtb : P.fdtb);
    }
    grid.sync();

    // P5: scan1 (32*G vb)
    for (int vb = bid; vb < 32 * P.G; vb += gsz) {
        int zz = vb >> 4, bb = (vb >> 3) & 1, bx = vb & 7;
        int dirv = (zz >= P.G) ? 1 : 0;
        int g = zz - (dirv ? P.G : 0);
        scan1_body(bx * 256 + tid, bb, dirv, g, P.G, P.Cn,
                   P.dtfb, P.xsb2, P.xdb2, P.fA, P.bA, P.hend, P.aprod);
    }
    grid.sync();

    // P6: scan2 (512 vb)
    for (int vb = bid; vb < 512; vb += gsz)
        scan2_body((vb & 255) * 256 + tid, vb >> 8, P.hend, P.aprod, P.G);
    grid.sync();

    // P7: scan3 (32*G vb)
    for (int vb = bid; vb < 32 * P.G; vb += gsz) {
        int zz = vb >> 4, bb = (vb >> 3) & 1, bx = vb & 7;
        int dirv = (zz >= P.G) ? 1 : 0;
        int g = zz - (dirv ? P.G : 0);
        scan3_body(bx * 256 + tid, bb, dirv, g, P.G, P.Cn,
                   P.dtfb, P.xsb2, P.xdb2, P.xz2, P.fA, P.bA, P.fD, P.bD,
                   P.hend, P.ycat);
    }
    grid.sync();

    // P8: final split-K GEMM (512 vb) -> fpart (aliases xz2, dead now)
    for (int vb = bid; vb < 512; vb += gsz) {
        int z = vb >> 7, rem = vb & 127;
        int bm = (rem >> 3) * 128, bn = (rem & 7) * 128;
        gemm_tile<0>(smem, tid,
            P.ycat + (size_t)z * 1024, 2 * DI,
            P.wcat + (size_t)z * 1024, 2 * DI,
            P.fpart + (size_t)z * MR * DM, DM,
            1024, bm, bn, nullptr);
    }
    grid.sync();

    // P9: final reduce (2048 vb)
    for (int vb = bid; vb < 2048; vb += gsz)
        freduce_body(((size_t)vb * 256 + tid) * 4, P.fpart, P.x, P.proj_b, P.outp);
}

// =================== fallback wrappers (multi-dispatch path) ===================
template<int EPI>
__global__ __launch_bounds__(256) void gemm_gl(
    const __hip_bfloat16* __restrict__ A, int lda, size_t aofs,
    const __hip_bfloat16* __restrict__ B, int ldb, size_t bofs,
    void* __restrict__ Cp, int ldc, size_t cofs, int K,
    const float* __restrict__ bias0, const float* __restrict__ bias1)
{
    __shared__ __hip_bfloat16 smem[2 * 128 * 64];
    const int z = blockIdx.z;
    void* Cz;
    if (EPI == 0) Cz = (float*)Cp + (size_t)z * cofs;
    else          Cz = (__hip_bfloat16*)Cp + (size_t)z * cofs;
    gemm_tile<EPI>(smem, threadIdx.x,
        A + (size_t)z * aofs, lda, B + (size_t)z * bofs, ldb,
        Cz, ldc, K, blockIdx.y * 128, blockIdx.x * 128,
        (EPI == 3) ? (z ? bias1 : bias0) : nullptr);
}

__global__ __launch_bounds__(256) void inproj_wcat_k(
    const __hip_bfloat16* __restrict__ nb,  const __hip_bfloat16* __restrict__ wbi,
    __hip_bfloat16* __restrict__ xz2,
    const __hip_bfloat16* __restrict__ pwb, const __hip_bfloat16* __restrict__ wot,
    __hip_bfloat16* __restrict__ wcat)
{
    __shared__ __hip_bfloat16 smem[2 * 128 * 64];
    const int z = blockIdx.z;
    const int bxv = blockIdx.x, byv = blockIdx.y;
    if (z >= 2 && (bxv >= 16 || byv >= 8)) return;
    const __hip_bfloat16 *Az, *Bz; __hip_bfloat16* Cz; int lda;
    if (z < 2) {
        Az = nb; lda = DM;
        Bz = wbi + (size_t)z * 2 * DI * DM;
        Cz = xz2 + (size_t)z * MR * 2 * DI;
    } else {
        Az = pwb + (size_t)(z - 2) * DM; lda = 2 * DM;
        Bz = wot + (size_t)(z - 2) * DI * DM;
        Cz = wcat + (size_t)(z - 2) * DI;
    }
    gemm_tile<1>(smem, threadIdx.x, Az, lda, Bz, DM, Cz, 2 * DI, DM,
                 byv * 128, bxv * 128, nullptr);
}

__global__ __launch_bounds__(256) void xproj_part_k(
    const __hip_bfloat16* __restrict__ A,
    const __hip_bfloat16* __restrict__ B,
    float* __restrict__ part)
{
    __shared__ __hip_bfloat16 smem[2 * 128 * 64];
    const int ks = blockIdx.x, z = blockIdx.z;
    const int kb = ks * (DI / KS);
    gemm_tile<0>(smem, threadIdx.x,
        A + (size_t)z * MR * DI + kb, DI,
        B + (size_t)z * 128 * DI + kb, DI,
        part + ((size_t)z * KS + ks) * MR * XLD, XLD,
        DI / KS, blockIdx.y * 128, 0, nullptr);
}

__global__ __launch_bounds__(256) void xproj_reduce_k(
    const float* __restrict__ part, float* __restrict__ xdb,
    __hip_bfloat16* __restrict__ xdbt)
{
    xreduce_body(((size_t)blockIdx.x * 256 + threadIdx.x) * 4, blockIdx.y,
                 part, xdb, xdbt);
}

__global__ __launch_bounds__(256) void conv_silu_k(
    const __hip_bfloat16* __restrict__ xz2,
    const float* __restrict__ fW, const float* __restrict__ fb,
    const float* __restrict__ bW, const float* __restrict__ bb_,
    __hip_bfloat16* __restrict__ xsb2)
{
    conv_body(blockIdx.x * 256 + threadIdx.x, xz2, fW, fb, bW, bb_, xsb2);
}

__global__ __launch_bounds__(256) void scan1_k(
    const __hip_bfloat16* __restrict__ dtf2, const __hip_bfloat16* __restrict__ xsb2,
    const float* __restrict__ xdb2,
    const float* __restrict__ fA, const float* __restrict__ bA,
    float* __restrict__ hend, float* __restrict__ aprod, int G, int Cn)
{
    int zz = blockIdx.z;
    int dirv = (zz >= G) ? 1 : 0;
    scan1_body(blockIdx.x * 256 + threadIdx.x, blockIdx.y, dirv,
               zz - (dirv ? G : 0), G, Cn, dtf2, xsb2, xdb2, fA, bA, hend, aprod);
}

__global__ __launch_bounds__(256) void scan2_k(
    float* __restrict__ hend, const float* __restrict__ aprod, int G)
{
    scan2_body(blockIdx.x * 256 + threadIdx.x, blockIdx.y, hend, aprod, G);
}

__global__ __launch_bounds__(256) void scan3_k(
    const __hip_bfloat16* __restrict__ dtf2, const __hip_bfloat16* __restrict__ xsb2,
    const float* __restrict__ xdb2, const __hip_bfloat16* __restrict__ xz2,
    const float* __restrict__ fA, const float* __restrict__ bA,
    const float* __restrict__ fD, const float* __restrict__ bD,
    const float* __restrict__ hin, __hip_bfloat16* __restrict__ ycat, int G, int Cn)
{
    int zz = blockIdx.z;
    int dirv = (zz >= G) ? 1 : 0;
    scan3_body(blockIdx.x * 256 + threadIdx.x, blockIdx.y, dirv,
               zz - (dirv ? G : 0), G, Cn, dtf2, xsb2, xdb2, xz2,
               fA, bA, fD, bD, hin, ycat);
}

__global__ __launch_bounds__(256) void scan_mono_k(
    const __hip_bfloat16* __restrict__ dtf2, const __hip_bfloat16* __restrict__ xsb2,
    const float* __restrict__ xdb2, const __hip_bfloat16* __restrict__ xz2,
    const float* __restrict__ fA, const float* __restrict__ bA,
    const float* __restrict__ fD, const float* __restrict__ bD,
    __hip_bfloat16* __restrict__ ycat)
{
    int d  = blockIdx.x * 256 + threadIdx.x;
    int bb = blockIdx.y;
    int dirv = blockIdx.z;
    const float* A_log = dirv ? bA : fA;
    const float* Dskip = dirv ? bD : fD;
    const __hip_bfloat16* dtf = dtf2 + (size_t)dirv * MR * DI;
    const __hip_bfloat16* xs = xsb2 + (size_t)dirv * MR * DI;
    const float* xdb = xdb2 + (size_t)dirv * MR * XLD;
    const __hip_bfloat16* xz = xz2 + (size_t)dirv * MR * 2 * DI;
    float Ad[DST], h[DST];
    #pragma unroll
    for (int s = 0; s < DST; ++s) { Ad[s] = -__expf(A_log[d * DST + s]); h[s] = 0.f; }
    float Dsk = Dskip[d];
    for (int i = 0; i < LL; ++i) {
        int t = dirv ? (LL - 1 - i) : i;
        size_t m = (size_t)bb * LL + t;
        float dtv = bf2f(dtf[m * DI + d]);
        float xv  = bf2f(xs[m * DI + d]);
        const float* bc = xdb + m * XLD;
        float dtx = dtv * xv;
        float yv = 0.f;
        #pragma unroll
        for (int s = 0; s < DST; ++s) {
            float dA = __expf(dtv * Ad[s]);
            h[s] = fmaf(h[s], dA, dtx * bc[64 + s]);
            yv = fmaf(h[s], bc[80 + s], yv);
        }
        float zv = bf2f(xz[m * (2 * DI) + DI + d]);
        ycat[m * (2 * DI) + (size_t)dirv * DI + d] =
            __float2bfloat16((yv + xv * Dsk) * siluf(zv));
    }
}

__global__ __launch_bounds__(256) void final_reduce_k(
    const float* __restrict__ part, const float* __restrict__ x,
    const float* __restrict__ proj_b, float* __restrict__ out)
{
    freduce_body(((size_t)blockIdx.x * 256 + threadIdx.x) * 4, part, x, proj_b, out);
}

// =================== launch ===================
extern "C" void kernel_launch(void* const* d_in, const int* in_sizes, int n_in,
                              void* d_out, int out_size, void* d_ws, size_t ws_size,
                              hipStream_t stream)
{
    const float* x      = (const float*)d_in[0];
    const float* ln_w   = (const float*)d_in[1];
    const float* ln_b   = (const float*)d_in[2];
    const float* f_inW    = (const float*)d_in[3];
    const float* f_convW  = (const float*)d_in[4];
    const float* f_convb  = (const float*)d_in[5];
    const float* f_xprojW = (const float*)d_in[6];
    const float* f_dtW    = (const float*)d_in[7];
    const float* f_dtb    = (const float*)d_in[8];
    const float* f_A_log  = (const float*)d_in[9];
    const float* f_Dskip  = (const float*)d_in[10];
    const float* f_outW   = (const float*)d_in[11];
    const float* b_inW    = (const float*)d_in[12];
    const float* b_convW  = (const float*)d_in[13];
    const float* b_convb  = (const float*)d_in[14];
    const float* b_xprojW = (const float*)d_in[15];
    const float* b_dtW    = (const float*)d_in[16];
    const float* b_dtb    = (const float*)d_in[17];
    const float* b_A_log  = (const float*)d_in[18];
    const float* b_Dskip  = (const float*)d_in[19];
    const float* b_outW   = (const float*)d_in[20];
    const float* proj_W = (const float*)d_in[21];
    const float* proj_b = (const float*)d_in[22];

    float* ws = (float*)d_ws;
    size_t o = 0;
    __hip_bfloat16* xz2  = (__hip_bfloat16*)(ws + o);
    float* fpart = ws + o;
    o += (size_t)2 * MR * 2 * DI / 2;
    __hip_bfloat16* xsb2 = (__hip_bfloat16*)(ws + o); o += (size_t)2 * MR * DI / 2;
    __hip_bfloat16* ycat = (__hip_bfloat16*)(ws + o);
    float* xpart = ws + o;
    o += (size_t)MR * 2 * DI / 2;
    float* xdb2 = ws + o; o += (size_t)2 * MR * XLD;
    __hip_bfloat16* xdbt = (__hip_bfloat16*)(ws + o); o += (size_t)2 * MR * 64 / 2;
    __hip_bfloat16* dtfb = (__hip_bfloat16*)(ws + o); o += (size_t)2 * MR * DI / 2;
    __hip_bfloat16* nb = (__hip_bfloat16*)(ws + o); o += (size_t)MR * DM / 2;
    __hip_bfloat16* warena = (__hip_bfloat16*)(ws + o); o += 15466496 / 2;
    float* hbuf = ws + o;
    size_t base_floats = o;

    __hip_bfloat16* wbi  = warena;               // [2][2DI][DM]
    __hip_bfloat16* pwb  = warena +  8388608;    // [DM][2DM]
    __hip_bfloat16* wdt  = warena + 10485760;    // [2][DI][64]
    __hip_bfloat16* wpb2 = warena + 10747904;    // [2][128][DI]
    __hip_bfloat16* wcat = warena + 11272192;    // [DM][2DI]

    const size_t slab = (size_t)NB * DI * DST;   // 65536
    int G = 32;
    while (G > 4 && (base_floats + 4ull * G * slab) * 4 > ws_size) G >>= 1;
    int useChunks = ((base_floats + 4ull * G * slab) * 4 <= ws_size);
    float* hend  = hbuf;
    float* aprod = hbuf + 2ull * G * slab;
    int Cn = useChunks ? LL / G : LL;

    int wotInHbuf = useChunks && (4ull * G * slab >= 2097152ull);
    __hip_bfloat16* wot = wotInHbuf ? (__hip_bfloat16*)hbuf : xz2;

    // cooperative-launch feasibility (host-side queries only; deterministic)
    int coop = 0;
    hipDeviceGetAttribute(&coop, hipDeviceAttributeCooperativeLaunch, 0);
    int occ = 0;
    if (coop) hipOccupancyMaxActiveBlocksPerMultiprocessor(&occ, mega_k, 256, 0);
    int gsz = occ * 256; if (gsz > 512) gsz = 512;
    bool mega_ok = useChunks && wotInHbuf && coop && gsz >= 256;

    // 1: mega-prep
    prep_k<<<13696, 256, 0, stream>>>(
        f_inW, b_inW, proj_W, f_dtW, b_dtW, warena,
        f_xprojW, b_xprojW, wpb2,
        f_outW, b_outW, wot,
        x, ln_w, ln_b, nb);

    if (mega_ok) {
        MegaArgs ma;
        ma.nb = nb; ma.wbi = wbi; ma.pwb = pwb; ma.wot = wot;
        ma.wpb2 = wpb2; ma.wdt = wdt;
        ma.xz2 = xz2; ma.wcat = wcat; ma.xsb2 = xsb2; ma.xdbt = xdbt;
        ma.dtfb = dtfb; ma.ycat = ycat;
        ma.fW = f_convW; ma.fb = f_convb; ma.bW = b_convW; ma.bb_ = b_convb;
        ma.xpart = xpart; ma.xdb2 = xdb2;
        ma.fdtb = f_dtb; ma.bdtb = b_dtb;
        ma.fA = f_A_log; ma.bA = b_A_log; ma.fD = f_Dskip; ma.bD = b_Dskip;
        ma.hend = hend; ma.aprod = aprod;
        ma.x = x; ma.proj_b = proj_b;
        ma.fpart = fpart; ma.outp = (float*)d_out;
        ma.G = G; ma.Cn = Cn;
        void* kp[] = { &ma };
        hipError_t e = hipLaunchCooperativeKernel(
            mega_k, dim3(gsz), dim3(256), kp, 0, stream);
        if (e == hipSuccess) return;
        // else fall through to the multi-dispatch path (deterministic per-call)
    }

    // ---------- fallback: R10 multi-dispatch path ----------
    if (wotInHbuf) {
        inproj_wcat_k<<<dim3(32, 16, 4), 256, 0, stream>>>(
            nb, wbi, xz2, pwb, wot, wcat);
    } else {
        gemm_gl<1><<<dim3(DI / 128, DM / 128, 2), 256, 0, stream>>>(
            pwb, 2 * DM, (size_t)DM, wot, DM, (size_t)DI * DM,
            wcat, 2 * DI, (size_t)DI, DM, nullptr, nullptr);
        inproj_wcat_k<<<dim3(32, 16, 2), 256, 0, stream>>>(
            nb, wbi, xz2, pwb, wot, wcat);
    }

    conv_silu_k<<<8192, 256, 0, stream>>>(
        xz2, f_convW, f_convb, b_convW, b_convb, xsb2);

    xproj_part_k<<<dim3(KS, MR / 128, 2), 256, 0, stream>>>(xsb2, wpb2, xpart);
    xproj_reduce_k<<<dim3((MR * XLD) / 1024, 2), 256, 0, stream>>>(xpart, xdb2, xdbt);

    gemm_gl<3><<<dim3(DI / 128, MR / 128, 2), 256, 0, stream>>>(
        xdbt, 64, (size_t)MR * 64, wdt, 64, (size_t)DI * 64,
        dtfb, DI, (size_t)MR * DI, 64, f_dtb, b_dtb);

    if (useChunks) {
        scan1_k<<<dim3(DI / 256, NB, 2 * G), 256, 0, stream>>>(
            dtfb, xsb2, xdb2, f_A_log, b_A_log, hend, aprod, G, Cn);
        scan2_k<<<dim3((NB * DI * DST) / 256, 2), 256, 0, stream>>>(hend, aprod, G);
        scan3_k<<<dim3(DI / 256, NB, 2 * G), 256, 0, stream>>>(
            dtfb, xsb2, xdb2, xz2, f_A_log, b_A_log, f_Dskip, b_Dskip,
            hend, ycat, G, Cn);
    } else {
        scan_mono_k<<<dim3(DI / 256, NB, 2), 256, 0, stream>>>(
            dtfb, xsb2, xdb2, xz2, f_A_log, b_A_log, f_Dskip, b_Dskip, ycat);
    }

    gemm_gl<0><<<dim3(DM / 128, MR / 128, 4), 256, 0, stream>>>(
        ycat, 2 * DI, 1024, wcat, 2 * DI, 1024,
        fpart, DM, (size_t)MR * DM, 1024, nullptr, nullptr);

    final_reduce_k<<<(MR * DM) / 1024, 256, 0, stream>>>(
        fpart, x, proj_b, (float*)d_out);
}